// Round 1
// baseline (163.413 us; speedup 1.0000x reference)
//
#include <hip/hip_runtime.h>

typedef unsigned short u16;
typedef unsigned int u32;
typedef __attribute__((ext_vector_type(8))) __bf16 bf16x8;
typedef __attribute__((ext_vector_type(4))) float f32x4;
typedef __attribute__((ext_vector_type(4))) u16 u16x4;

#define MFMA16(a, b, c) __builtin_amdgcn_mfma_f32_16x16x32_bf16((a), (b), (c), 0, 0, 0)

static __device__ __forceinline__ u16 f2b(float f) {
  union { float f; u32 u; } v; v.f = f;
  u32 u = v.u;
  return (u16)((u + 0x7FFFu + ((u >> 16) & 1u)) >> 16);
}

static __device__ __forceinline__ void gload16(const u16* gp, u16* lp) {
  __builtin_amdgcn_global_load_lds((__attribute__((address_space(1))) void*)(u16*)gp,
                                   (__attribute__((address_space(3))) void*)lp, 16, 0, 0);
}

// ---------------- prep kernels ----------------

// src [K][N] f32  ->  dst [N][K] bf16
__global__ __launch_bounds__(256) void k_transpose_f32_bf16(const float* __restrict__ src,
                                                            u16* __restrict__ dst, int K, int N) {
  __shared__ float tile[32][33];
  const int n0 = blockIdx.x * 32, k0 = blockIdx.y * 32;
  const int t = threadIdx.x;
  const int r = t >> 3, c4 = (t & 7) << 2;
  const float4 in4 = *(const float4*)(src + (size_t)(k0 + r) * N + n0 + c4);
  tile[r][c4 + 0] = in4.x; tile[r][c4 + 1] = in4.y;
  tile[r][c4 + 2] = in4.z; tile[r][c4 + 3] = in4.w;
  __syncthreads();
  u16x4 o;
  o.x = f2b(tile[c4 + 0][r]); o.y = f2b(tile[c4 + 1][r]);
  o.z = f2b(tile[c4 + 2][r]); o.w = f2b(tile[c4 + 3][r]);
  *(u16x4*)(dst + (size_t)(n0 + r) * K + k0 + c4) = o;
}

// W1p/W2p [1024][64] f32 -> WB rows 3072..3199 ([128][1024] bf16, transposed)
__global__ __launch_bounds__(256) void k_pw(const float* __restrict__ W1p, const float* __restrict__ W2p,
                                            u16* __restrict__ WBp) {
  const int idx = blockIdx.x * 256 + threadIdx.x;  // 131072 items
  const int j = idx >> 10, k = idx & 1023;
  const float v = (j < 64) ? W1p[(size_t)k * 64 + j] : W2p[(size_t)k * 64 + (j - 64)];
  WBp[idx] = f2b(v);
}

__global__ __launch_bounds__(256) void k_conv_x(const float* __restrict__ x, u16* __restrict__ xb) {
  const size_t idx = ((size_t)blockIdx.x * 256 + threadIdx.x) << 2;
  const float4 v = *(const float4*)(x + idx);
  u16x4 o; o.x = f2b(v.x); o.y = f2b(v.y); o.z = f2b(v.z); o.w = f2b(v.w);
  *(u16x4*)(xb + idx) = o;
}

// ---------------- 128x128 bf16 MFMA GEMM core (BK=64, global_load_lds, XOR swizzle) ----------------
// A [M][K] bf16 row-major, B [N][K] bf16 row-major (i.e. B pre-transposed). K multiple of 64.
static __device__ __forceinline__ void gemm128_core(const u16* __restrict__ A, const u16* __restrict__ B,
                                                    int brow, int bcol, int K,
                                                    u16* ldsA, u16* ldsB, f32x4 acc[4][4]) {
  const int tid = threadIdx.x;
  const int wave = tid >> 6, lane = tid & 63;
  const int wr = wave >> 1, wc = wave & 1;
  const int g = lane >> 4, l15 = lane & 15;

  for (int k0 = 0; k0 < K; k0 += 64) {
#pragma unroll
    for (int li = 0; li < 4; ++li) {
      const int f = li * 256 + wave * 64 + lane;   // 16B chunk index in [0,1024)
      const int row = f >> 3;
      const int slot = f & 7;
      const int gcol = ((slot ^ (row & 7)) << 3);  // pre-swizzled global source col
      const u16* ga = A + (size_t)(brow + row) * K + k0 + gcol;
      const u16* gb = B + (size_t)(bcol + row) * K + k0 + gcol;
      u16* la = ldsA + (size_t)(li * 256 + wave * 64) * 8;  // wave-uniform base
      u16* lb = ldsB + (size_t)(li * 256 + wave * 64) * 8;
      gload16(ga, la);
      gload16(gb, lb);
    }
    __syncthreads();
    bf16x8 af[4][2], bfr[4][2];
#pragma unroll
    for (int m = 0; m < 4; ++m) {
#pragma unroll
      for (int kk = 0; kk < 2; ++kk) {
        const int rowA = wr * 64 + m * 16 + l15;
        const int chA = (kk * 4 + g) ^ (rowA & 7);
        af[m][kk] = *(const bf16x8*)(ldsA + (size_t)rowA * 64 + chA * 8);
        const int rowB = wc * 64 + m * 16 + l15;
        const int chB = (kk * 4 + g) ^ (rowB & 7);
        bfr[m][kk] = *(const bf16x8*)(ldsB + (size_t)rowB * 64 + chB * 8);
      }
    }
#pragma unroll
    for (int m = 0; m < 4; ++m)
#pragma unroll
      for (int n = 0; n < 4; ++n)
#pragma unroll
        for (int kk = 0; kk < 2; ++kk)
          acc[m][n] = MFMA16(af[m][kk], bfr[n][kk], acc[m][n]);
    __syncthreads();
  }
}

// ---------------- GEMM1: x @ [Wqkv|W1p|W2p]  (M=2048, N=3200, K=1024) ----------------
__global__ __launch_bounds__(256) void k_gemm_qkvp(const u16* __restrict__ xb, const u16* __restrict__ WB,
                                                   const float* __restrict__ bqkv,
                                                   u16* __restrict__ Qext, u16* __restrict__ Kext,
                                                   u16* __restrict__ Vt, float* __restrict__ P12) {
  __shared__ __align__(16) u16 ldsA[128 * 64];
  __shared__ __align__(16) u16 ldsB[128 * 64];
  const int bid = blockIdx.x;
  const int bn = bid % 25, bm = bid / 25;
  f32x4 acc[4][4];
#pragma unroll
  for (int m = 0; m < 4; ++m)
#pragma unroll
    for (int n = 0; n < 4; ++n) acc[m][n] = (f32x4){0.f, 0.f, 0.f, 0.f};
  gemm128_core(xb, WB, bm * 128, bn * 128, 1024, ldsA, ldsB, acc);

  const int tid = threadIdx.x;
  const int wave = tid >> 6, lane = tid & 63;
  const int wr = wave >> 1, wc = wave & 1;
  const int g = lane >> 4, l15 = lane & 15;
  const int tbase = bm * 128 + wr * 64 + g * 4;
  const int cbase = bn * 128 + wc * 64 + l15;
#pragma unroll
  for (int m = 0; m < 4; ++m) {
#pragma unroll
    for (int n = 0; n < 4; ++n) {
      const int c = cbase + n * 16;
#pragma unroll
      for (int r = 0; r < 4; ++r) {
        const int t = tbase + m * 16 + r;
        float v = acc[m][n][r];
        if (c < 3072) {
          v += bqkv[c];
          const int sub = c >> 10;
          const int rem = c & 1023;
          const int hh = rem >> 6, d = rem & 63;
          if (sub == 0)      Qext[((size_t)hh * 2048 + t) * 96 + d] = f2b(v * 0.125f);
          else if (sub == 1) Kext[((size_t)hh * 2048 + t) * 96 + d] = f2b(v);
          else               Vt[((size_t)hh * 64 + d) * 2048 + t] = f2b(v);
        } else {
          P12[(size_t)t * 128 + (c - 3072)] = v;
        }
      }
    }
  }
}

// ---------------- Plucker lines -> Qext/Kext cols 64..95 ----------------
__global__ __launch_bounds__(256) void k_lines(const float* __restrict__ P12, const float* __restrict__ pscale,
                                               u16* __restrict__ Qext, u16* __restrict__ Kext) {
  const int idx = blockIdx.x * 256 + threadIdx.x;  // 32768 = 2048*16
  const int t = idx >> 4, h = idx & 15;
  const float* p = P12 + (size_t)t * 128;
  const float a0 = p[h * 4 + 0], a1 = p[h * 4 + 1], a2 = p[h * 4 + 2], a3 = p[h * 4 + 3];
  const float b0 = p[64 + h * 4 + 0], b1 = p[64 + h * 4 + 1], b2 = p[64 + h * 4 + 2], b3 = p[64 + h * 4 + 3];
  float L0 = a0 * b1 - a1 * b0;
  float L1 = a0 * b2 - a2 * b0;
  float L2 = a0 * b3 - a3 * b0;
  float L3 = a1 * b2 - a2 * b1;
  float L4 = a1 * b3 - a3 * b1;
  float L5 = a2 * b3 - a3 * b2;
  const float nrm = sqrtf(L0 * L0 + L1 * L1 + L2 * L2 + L3 * L3 + L4 * L4 + L5 * L5);
  const float inv = 1.0f / fmaxf(nrm, 1e-12f);
  L0 *= inv; L1 *= inv; L2 *= inv; L3 *= inv; L4 *= inv; L5 *= inv;
  const float s = pscale[h];
  u16* q = Qext + ((size_t)h * 2048 + t) * 96 + 64;
  u16* k = Kext + ((size_t)h * 2048 + t) * 96 + 64;
  q[0] = f2b(L0 * s); q[1] = f2b(L1 * s); q[2] = f2b(L2 * s);
  q[3] = f2b(L3 * s); q[4] = f2b(L4 * s); q[5] = f2b(L5 * s);
  // Jlines = J6 @ L : [L5, -L4, L3, L2, -L1, L0]
  k[0] = f2b(L5); k[1] = f2b(-L4); k[2] = f2b(L3);
  k[3] = f2b(L2); k[4] = f2b(-L1); k[5] = f2b(L0);
#pragma unroll
  for (int c = 6; c < 32; ++c) { q[c] = 0; k[c] = 0; }
}

// ---------------- fused causal attention (flash-style), K=96 (qk + plucker bias) ----------------
__global__ __launch_bounds__(256) void k_attn(const u16* __restrict__ Qext, const u16* __restrict__ Kext,
                                              const u16* __restrict__ Vt, u16* __restrict__ AO) {
  __shared__ __align__(16) u16 P_lds[4][16][40];  // per-wave, row stride 80B -> 2-way max
  const int idx = blockIdx.x;                     // 512 blocks
  const int half = idx >> 8;
  const int qt_raw = (idx & 255) >> 4;
  const int qt = half ? (31 - qt_raw) : qt_raw;   // pair long+short tiles per CU
  const int h = idx & 15;                         // consecutive blocks -> head%8 ~ XCD affinity
  const int wave = threadIdx.x >> 6, lane = threadIdx.x & 63;
  const int g = lane >> 4, l15 = lane & 15;
  const int q0 = qt * 64 + wave * 16;
  const u16* Qh = Qext + (size_t)h * 2048 * 96;
  const u16* Kh = Kext + (size_t)h * 2048 * 96;
  const u16* Vh = Vt + (size_t)h * 64 * 2048;

  bf16x8 aq[3];
#pragma unroll
  for (int ks = 0; ks < 3; ++ks)
    aq[ks] = *(const bf16x8*)(Qh + (size_t)(q0 + l15) * 96 + ks * 32 + g * 8);

  f32x4 accO[4];
#pragma unroll
  for (int n = 0; n < 4; ++n) accO[n] = (f32x4){0.f, 0.f, 0.f, 0.f};
  float mrun[4] = {-1e30f, -1e30f, -1e30f, -1e30f};
  float lrun[4] = {0.f, 0.f, 0.f, 0.f};
  u16(*Pw)[40] = P_lds[wave];

  const int jt_max = (q0 + 15) >> 5;
  for (int jt = 0; jt <= jt_max; ++jt) {
    const int jb = jt * 32;
    f32x4 S0 = (f32x4){0.f, 0.f, 0.f, 0.f};
    f32x4 S1 = (f32x4){0.f, 0.f, 0.f, 0.f};
#pragma unroll
    for (int ks = 0; ks < 3; ++ks) {
      bf16x8 bk0 = *(const bf16x8*)(Kh + (size_t)(jb + l15) * 96 + ks * 32 + g * 8);
      bf16x8 bk1 = *(const bf16x8*)(Kh + (size_t)(jb + 16 + l15) * 96 + ks * 32 + g * 8);
      S0 = MFMA16(aq[ks], bk0, S0);
      S1 = MFMA16(aq[ks], bk1, S1);
    }
    if (jb + 31 > q0) {  // causal mask possible in this tile
      const int j0 = jb + l15, j1 = jb + 16 + l15;
      const int ib = q0 + g * 4;
#pragma unroll
      for (int r = 0; r < 4; ++r) {
        if (j0 > ib + r) S0[r] = -1e30f;
        if (j1 > ib + r) S1[r] = -1e30f;
      }
    }
    float alpha[4];
#pragma unroll
    for (int r = 0; r < 4; ++r) {
      float mx = fmaxf(S0[r], S1[r]);
      mx = fmaxf(mx, __shfl_xor(mx, 1));
      mx = fmaxf(mx, __shfl_xor(mx, 2));
      mx = fmaxf(mx, __shfl_xor(mx, 4));
      mx = fmaxf(mx, __shfl_xor(mx, 8));
      const float mn = fmaxf(mrun[r], mx);
      alpha[r] = __expf(mrun[r] - mn);
      mrun[r] = mn;
      const float p0 = __expf(S0[r] - mn);
      const float p1 = __expf(S1[r] - mn);
      S0[r] = p0; S1[r] = p1;
      float rs = p0 + p1;
      rs += __shfl_xor(rs, 1);
      rs += __shfl_xor(rs, 2);
      rs += __shfl_xor(rs, 4);
      rs += __shfl_xor(rs, 8);
      lrun[r] = lrun[r] * alpha[r] + rs;
    }
#pragma unroll
    for (int n = 0; n < 4; ++n)
#pragma unroll
      for (int r = 0; r < 4; ++r) accO[n][r] *= alpha[r];
    // P -> LDS (D-layout) then read back as A-fragment
#pragma unroll
    for (int r = 0; r < 4; ++r) {
      Pw[g * 4 + r][l15] = f2b(S0[r]);
      Pw[g * 4 + r][16 + l15] = f2b(S1[r]);
    }
    const bf16x8 pa = *(const bf16x8*)(&Pw[l15][g * 8]);
#pragma unroll
    for (int n = 0; n < 4; ++n) {
      bf16x8 bv = *(const bf16x8*)(Vh + (size_t)(n * 16 + l15) * 2048 + jb + g * 8);
      accO[n] = MFMA16(pa, bv, accO[n]);
    }
  }
#pragma unroll
  for (int r = 0; r < 4; ++r) {
    const float inv = 1.0f / lrun[r];
    const size_t base = (size_t)(q0 + g * 4 + r) * 1024 + h * 64 + l15;
    AO[base + 0]  = f2b(accO[0][r] * inv);
    AO[base + 16] = f2b(accO[1][r] * inv);
    AO[base + 32] = f2b(accO[2][r] * inv);
    AO[base + 48] = f2b(accO[3][r] * inv);
  }
}

// ---------------- GEMM out: AO @ WoutT + bout  (M=2048, N=1024, K=1024) ----------------
__global__ __launch_bounds__(256) void k_gemm_out(const u16* __restrict__ AO, const u16* __restrict__ WoT,
                                                  const float* __restrict__ bout, float* __restrict__ out) {
  __shared__ __align__(16) u16 ldsA[128 * 64];
  __shared__ __align__(16) u16 ldsB[128 * 64];
  const int bid = blockIdx.x;
  const int bn = bid & 7, bm = bid >> 3;
  f32x4 acc[4][4];
#pragma unroll
  for (int m = 0; m < 4; ++m)
#pragma unroll
    for (int n = 0; n < 4; ++n) acc[m][n] = (f32x4){0.f, 0.f, 0.f, 0.f};
  gemm128_core(AO, WoT, bm * 128, bn * 128, 1024, ldsA, ldsB, acc);

  const int tid = threadIdx.x;
  const int wave = tid >> 6, lane = tid & 63;
  const int wr = wave >> 1, wc = wave & 1;
  const int g = lane >> 4, l15 = lane & 15;
  const int tbase = bm * 128 + wr * 64 + g * 4;
  const int cbase = bn * 128 + wc * 64 + l15;
#pragma unroll
  for (int m = 0; m < 4; ++m)
#pragma unroll
    for (int n = 0; n < 4; ++n) {
      const int c = cbase + n * 16;
      const float bb = bout[c];
#pragma unroll
      for (int r = 0; r < 4; ++r) {
        const int t = tbase + m * 16 + r;
        out[(size_t)t * 1024 + c] = acc[m][n][r] + bb;
      }
    }
}

// ---------------- launch ----------------
extern "C" void kernel_launch(void* const* d_in, const int* in_sizes, int n_in,
                              void* d_out, int out_size, void* d_ws, size_t ws_size,
                              hipStream_t stream) {
  const float* x      = (const float*)d_in[0];
  const float* Wqkv   = (const float*)d_in[1];
  const float* bqkv   = (const float*)d_in[2];
  const float* W1p    = (const float*)d_in[3];
  const float* W2p    = (const float*)d_in[4];
  const float* pscale = (const float*)d_in[5];
  const float* Wout   = (const float*)d_in[6];
  const float* bout   = (const float*)d_in[7];
  float* out = (float*)d_out;

  char* ws = (char*)d_ws;
  u16*   WB    = (u16*)(ws + 0);          // [3200][1024] bf16 (transposed weights)
  u16*   WoT   = (u16*)(ws + 6553600);    // [1024][1024] bf16
  u16*   xb    = (u16*)(ws + 8650752);    // [2048][1024] bf16
  u16*   Qext  = (u16*)(ws + 12845056);   // [16][2048][96] bf16 (q/8 | s*L | 0)
  u16*   Kext  = (u16*)(ws + 19136512);   // [16][2048][96] bf16 (k | J·L | 0)
  u16*   Vt    = (u16*)(ws + 25427968);   // [16][64][2048] bf16
  float* P12   = (float*)(ws + 29622272); // [2048][128] f32
  u16*   AO    = (u16*)(ws + 30670848);   // [2048][1024] bf16

  k_transpose_f32_bf16<<<dim3(96, 32), 256, 0, stream>>>(Wqkv, WB, 1024, 3072);
  k_pw<<<512, 256, 0, stream>>>(W1p, W2p, WB + (size_t)3072 * 1024);
  k_transpose_f32_bf16<<<dim3(32, 32), 256, 0, stream>>>(Wout, WoT, 1024, 1024);
  k_conv_x<<<2048, 256, 0, stream>>>(x, xb);
  k_gemm_qkvp<<<400, 256, 0, stream>>>(xb, WB, bqkv, Qext, Kext, Vt, P12);
  k_lines<<<128, 256, 0, stream>>>(P12, pscale, Qext, Kext);
  k_attn<<<512, 256, 0, stream>>>(Qext, Kext, Vt, AO);
  k_gemm_out<<<128, 256, 0, stream>>>(AO, WoT, bout, out);
}

// Round 2
// 127.556 us; speedup vs baseline: 1.2811x; 1.2811x over previous
//
#include <hip/hip_runtime.h>

typedef unsigned short u16;
typedef unsigned int u32;
typedef __attribute__((ext_vector_type(8))) __bf16 bf16x8;
typedef __attribute__((ext_vector_type(4))) float f32x4;
typedef __attribute__((ext_vector_type(4))) u16 u16x4;

#define MFMA16(a, b, c) __builtin_amdgcn_mfma_f32_16x16x32_bf16((a), (b), (c), 0, 0, 0)

static __device__ __forceinline__ u16 f2b(float f) {
  union { float f; u32 u; } v; v.f = f;
  u32 u = v.u;
  return (u16)((u + 0x7FFFu + ((u >> 16) & 1u)) >> 16);
}

// packed f32x2 -> bf16x2 (RNE), low half = a
static __device__ __forceinline__ u32 pack2(float a, float b) {
  u32 r;
  asm("v_cvt_pk_bf16_f32 %0, %1, %2" : "=v"(r) : "v"(a), "v"(b));
  return r;
}

static __device__ __forceinline__ void gload16(const u16* gp, u16* lp) {
  __builtin_amdgcn_global_load_lds((__attribute__((address_space(1))) void*)(u16*)gp,
                                   (__attribute__((address_space(3))) void*)lp, 16, 0, 0);
}

// ---------------- prep kernels ----------------

// src [K][N] f32  ->  dst [N][K] bf16
__global__ __launch_bounds__(256) void k_transpose_f32_bf16(const float* __restrict__ src,
                                                            u16* __restrict__ dst, int K, int N) {
  __shared__ float tile[32][33];
  const int n0 = blockIdx.x * 32, k0 = blockIdx.y * 32;
  const int t = threadIdx.x;
  const int r = t >> 3, c4 = (t & 7) << 2;
  const float4 in4 = *(const float4*)(src + (size_t)(k0 + r) * N + n0 + c4);
  tile[r][c4 + 0] = in4.x; tile[r][c4 + 1] = in4.y;
  tile[r][c4 + 2] = in4.z; tile[r][c4 + 3] = in4.w;
  __syncthreads();
  u16x4 o;
  o.x = f2b(tile[c4 + 0][r]); o.y = f2b(tile[c4 + 1][r]);
  o.z = f2b(tile[c4 + 2][r]); o.w = f2b(tile[c4 + 3][r]);
  *(u16x4*)(dst + (size_t)(n0 + r) * K + k0 + c4) = o;
}

// W1p/W2p [1024][64] f32 -> WB rows 3072..3199 ([128][1024] bf16, transposed)
__global__ __launch_bounds__(256) void k_pw(const float* __restrict__ W1p, const float* __restrict__ W2p,
                                            u16* __restrict__ WBp) {
  const int idx = blockIdx.x * 256 + threadIdx.x;  // 131072 items
  const int j = idx >> 10, k = idx & 1023;
  const float v = (j < 64) ? W1p[(size_t)k * 64 + j] : W2p[(size_t)k * 64 + (j - 64)];
  WBp[idx] = f2b(v);
}

__global__ __launch_bounds__(256) void k_conv_x(const float* __restrict__ x, u16* __restrict__ xb) {
  const size_t idx = ((size_t)blockIdx.x * 256 + threadIdx.x) << 2;
  const float4 v = *(const float4*)(x + idx);
  u16x4 o; o.x = f2b(v.x); o.y = f2b(v.y); o.z = f2b(v.z); o.w = f2b(v.w);
  *(u16x4*)(xb + idx) = o;
}

// ---------------- 128x64 bf16 MFMA GEMM core (BK=64, global_load_lds, XOR swizzle) ----------------
// A [M][K] bf16 row-major, B [N][K] bf16 row-major (pre-transposed). K multiple of 64.
// Tile: 128 rows x 64 cols, 4 waves (2x2), per-wave 64x32, acc[4][2].
static __device__ __forceinline__ void gemm_core_128x64(const u16* __restrict__ A, const u16* __restrict__ B,
                                                        int brow, int bcol, int K,
                                                        u16* ldsA, u16* ldsB, f32x4 acc[4][2]) {
  const int tid = threadIdx.x;
  const int wave = tid >> 6, lane = tid & 63;
  const int wr = wave >> 1, wc = wave & 1;
  const int g = lane >> 4, l15 = lane & 15;

  for (int k0 = 0; k0 < K; k0 += 64) {
#pragma unroll
    for (int li = 0; li < 4; ++li) {
      const int f = li * 256 + wave * 64 + lane;   // A: 16B chunk index in [0,1024)
      const int row = f >> 3;
      const int slot = f & 7;
      const int gcol = ((slot ^ (row & 7)) << 3);  // pre-swizzled global source col
      gload16(A + (size_t)(brow + row) * K + k0 + gcol, ldsA + (size_t)(li * 256 + wave * 64) * 8);
    }
#pragma unroll
    for (int li = 0; li < 2; ++li) {
      const int f = li * 256 + wave * 64 + lane;   // B: 16B chunk index in [0,512)
      const int row = f >> 3;
      const int slot = f & 7;
      const int gcol = ((slot ^ (row & 7)) << 3);
      gload16(B + (size_t)(bcol + row) * K + k0 + gcol, ldsB + (size_t)(li * 256 + wave * 64) * 8);
    }
    __syncthreads();
    bf16x8 af[4][2], bfr[2][2];
#pragma unroll
    for (int kk = 0; kk < 2; ++kk) {
#pragma unroll
      for (int m = 0; m < 4; ++m) {
        const int rowA = wr * 64 + m * 16 + l15;
        const int chA = (kk * 4 + g) ^ (rowA & 7);
        af[m][kk] = *(const bf16x8*)(ldsA + (size_t)rowA * 64 + chA * 8);
      }
#pragma unroll
      for (int n = 0; n < 2; ++n) {
        const int rowB = wc * 32 + n * 16 + l15;
        const int chB = (kk * 4 + g) ^ (rowB & 7);
        bfr[n][kk] = *(const bf16x8*)(ldsB + (size_t)rowB * 64 + chB * 8);
      }
    }
#pragma unroll
    for (int m = 0; m < 4; ++m)
#pragma unroll
      for (int n = 0; n < 2; ++n)
#pragma unroll
        for (int kk = 0; kk < 2; ++kk)
          acc[m][n] = MFMA16(af[m][kk], bfr[n][kk], acc[m][n]);
    __syncthreads();
  }
}

// ---------------- GEMM1: x @ [Wqkv|W1p|W2p]  (M=2048, N=3200, K=1024) ----------------
__global__ __launch_bounds__(256) void k_gemm_qkvp(const u16* __restrict__ xb, const u16* __restrict__ WB,
                                                   const float* __restrict__ bqkv,
                                                   u16* __restrict__ Qext, u16* __restrict__ Kext,
                                                   u16* __restrict__ Vt, float* __restrict__ P12) {
  __shared__ __align__(16) u16 ldsA[128 * 64];
  __shared__ __align__(16) u16 ldsB[64 * 64];
  const int bid = blockIdx.x;                      // 800 blocks
  const int bn = bid % 50, bm = bid / 50;
  f32x4 acc[4][2];
#pragma unroll
  for (int m = 0; m < 4; ++m)
#pragma unroll
    for (int n = 0; n < 2; ++n) acc[m][n] = (f32x4){0.f, 0.f, 0.f, 0.f};
  gemm_core_128x64(xb, WB, bm * 128, bn * 64, 1024, ldsA, ldsB, acc);

  const int tid = threadIdx.x;
  const int wave = tid >> 6, lane = tid & 63;
  const int wr = wave >> 1, wc = wave & 1;
  const int g = lane >> 4, l15 = lane & 15;
  const int tbase = bm * 128 + wr * 64 + g * 4;
  const int cbase = bn * 64 + wc * 32 + l15;
#pragma unroll
  for (int m = 0; m < 4; ++m) {
#pragma unroll
    for (int n = 0; n < 2; ++n) {
      const int c = cbase + n * 16;
#pragma unroll
      for (int r = 0; r < 4; ++r) {
        const int t = tbase + m * 16 + r;
        float v = acc[m][n][r];
        if (c < 3072) {
          v += bqkv[c];
          const int sub = c >> 10;
          const int rem = c & 1023;
          const int hh = rem >> 6, d = rem & 63;
          if (sub == 0)      Qext[((size_t)hh * 2048 + t) * 96 + d] = f2b(v * 0.125f);
          else if (sub == 1) Kext[((size_t)hh * 2048 + t) * 96 + d] = f2b(v);
          else               Vt[((size_t)hh * 64 + d) * 2048 + t] = f2b(v);
        } else {
          P12[(size_t)t * 128 + (c - 3072)] = v;
        }
      }
    }
  }
}

// ---------------- Plucker lines -> Qext/Kext cols 64..95 ----------------
__global__ __launch_bounds__(256) void k_lines(const float* __restrict__ P12, const float* __restrict__ pscale,
                                               u16* __restrict__ Qext, u16* __restrict__ Kext) {
  const int idx = blockIdx.x * 256 + threadIdx.x;  // 32768 = 2048*16
  const int t = idx >> 4, h = idx & 15;
  const float* p = P12 + (size_t)t * 128;
  const float a0 = p[h * 4 + 0], a1 = p[h * 4 + 1], a2 = p[h * 4 + 2], a3 = p[h * 4 + 3];
  const float b0 = p[64 + h * 4 + 0], b1 = p[64 + h * 4 + 1], b2 = p[64 + h * 4 + 2], b3 = p[64 + h * 4 + 3];
  float L0 = a0 * b1 - a1 * b0;
  float L1 = a0 * b2 - a2 * b0;
  float L2 = a0 * b3 - a3 * b0;
  float L3 = a1 * b2 - a2 * b1;
  float L4 = a1 * b3 - a3 * b1;
  float L5 = a2 * b3 - a3 * b2;
  const float nrm = sqrtf(L0 * L0 + L1 * L1 + L2 * L2 + L3 * L3 + L4 * L4 + L5 * L5);
  const float inv = 1.0f / fmaxf(nrm, 1e-12f);
  L0 *= inv; L1 *= inv; L2 *= inv; L3 *= inv; L4 *= inv; L5 *= inv;
  const float s = pscale[h];
  u16* q = Qext + ((size_t)h * 2048 + t) * 96 + 64;
  u16* k = Kext + ((size_t)h * 2048 + t) * 96 + 64;
  q[0] = f2b(L0 * s); q[1] = f2b(L1 * s); q[2] = f2b(L2 * s);
  q[3] = f2b(L3 * s); q[4] = f2b(L4 * s); q[5] = f2b(L5 * s);
  // Jlines = J6 @ L : [L5, -L4, L3, L2, -L1, L0]
  k[0] = f2b(L5); k[1] = f2b(-L4); k[2] = f2b(L3);
  k[3] = f2b(L2); k[4] = f2b(-L1); k[5] = f2b(L0);
#pragma unroll
  for (int c = 6; c < 32; ++c) { q[c] = 0; k[c] = 0; }
}

// ---------------- fused causal attention, swapped-operand (S^T), in-register softmax ----------------
// Per block: 4 waves x 16 q rows. S^T = mfma(K,Q): lane holds col q=lane&15, rows k=(lane>>4)*4+r.
// O^T = mfma(V^T, P^T): lane holds col q=lane&15, rows d. m/l/alpha are lane-local (per q).
__global__ __launch_bounds__(256) void k_attn(const u16* __restrict__ Qext, const u16* __restrict__ Kext,
                                              const u16* __restrict__ Vt, u16* __restrict__ AO) {
  const int idx = blockIdx.x;                     // 512 blocks
  const int half = idx >> 8;
  const int qt_raw = (idx & 255) >> 4;
  const int qt = half ? (31 - qt_raw) : qt_raw;   // pair long+short tiles per CU
  const int h = idx & 15;
  const int wave = threadIdx.x >> 6, lane = threadIdx.x & 63;
  const int g = lane >> 4, l15 = lane & 15;
  const int q0 = qt * 64 + wave * 16;
  const int q_glob = q0 + l15;
  const u16* Qh = Qext + (size_t)h * 2048 * 96;
  const u16* Kh = Kext + (size_t)h * 2048 * 96;
  const u16* Vh = Vt + (size_t)h * 64 * 2048;

  bf16x8 aq[3];  // Q as B-fragment: col q=l15, contraction c = ks*32 + g*8 + e
#pragma unroll
  for (int ks = 0; ks < 3; ++ks)
    aq[ks] = *(const bf16x8*)(Qh + (size_t)q_glob * 96 + ks * 32 + g * 8);

  f32x4 accO[4];
#pragma unroll
  for (int n = 0; n < 4; ++n) accO[n] = (f32x4){0.f, 0.f, 0.f, 0.f};
  float mrun = -1e30f, lrun = 0.f;

  const int jt_max = (q0 + 15) >> 5;
  const u16* Kbase = Kh + (size_t)l15 * 96 + g * 8;

  bf16x8 kA0[3], kA1[3], kB0[3], kB1[3];
#pragma unroll
  for (int ks = 0; ks < 3; ++ks) {
    kA0[ks] = *(const bf16x8*)(Kbase + ks * 32);
    kA1[ks] = *(const bf16x8*)(Kbase + 16 * 96 + ks * 32);
  }

#define ATTN_STEP(KC0, KC1, KN0, KN1)                                             \
  {                                                                               \
    const int jb = jt * 32;                                                       \
    f32x4 S0 = (f32x4){0.f, 0.f, 0.f, 0.f}, S1 = (f32x4){0.f, 0.f, 0.f, 0.f};     \
    __builtin_amdgcn_s_setprio(1);                                                \
    _Pragma("unroll")                                                             \
    for (int ks = 0; ks < 3; ++ks) {                                              \
      S0 = MFMA16(KC0[ks], aq[ks], S0);                                           \
      S1 = MFMA16(KC1[ks], aq[ks], S1);                                           \
    }                                                                             \
    __builtin_amdgcn_s_setprio(0);                                                \
    const int jbn = (jt < jt_max) ? jb + 32 : jb;                                 \
    const u16* kp = Kbase + (size_t)jbn * 96;                                     \
    _Pragma("unroll")                                                             \
    for (int ks = 0; ks < 3; ++ks) {                                              \
      KN0[ks] = *(const bf16x8*)(kp + ks * 32);                                   \
      KN1[ks] = *(const bf16x8*)(kp + 16 * 96 + ks * 32);                         \
    }                                                                             \
    bf16x8 av[4];                                                                 \
    _Pragma("unroll")                                                             \
    for (int n = 0; n < 4; ++n)                                                   \
      av[n] = *(const bf16x8*)(Vh + (size_t)(n * 16 + l15) * 2048 + jb + g * 8);  \
    if (jb + 31 > q0) {                                                           \
      _Pragma("unroll")                                                           \
      for (int r = 0; r < 4; ++r) {                                               \
        if (jb + g * 4 + r > q_glob) S0[r] = -1e30f;                              \
        if (jb + 16 + g * 4 + r > q_glob) S1[r] = -1e30f;                         \
      }                                                                           \
    }                                                                             \
    float pm = fmaxf(fmaxf(fmaxf(S0[0], S0[1]), fmaxf(S0[2], S0[3])),             \
                     fmaxf(fmaxf(S1[0], S1[1]), fmaxf(S1[2], S1[3])));            \
    pm = fmaxf(pm, __shfl_xor(pm, 16));                                           \
    pm = fmaxf(pm, __shfl_xor(pm, 32));                                           \
    const float mn = fmaxf(mrun, pm);                                             \
    const float alpha = __expf(mrun - mn);                                        \
    mrun = mn;                                                                    \
    _Pragma("unroll")                                                             \
    for (int r = 0; r < 4; ++r) {                                                 \
      S0[r] = __expf(S0[r] - mn);                                                 \
      S1[r] = __expf(S1[r] - mn);                                                 \
    }                                                                             \
    float rs = ((S0[0] + S0[1]) + (S0[2] + S0[3])) + ((S1[0] + S1[1]) + (S1[2] + S1[3])); \
    rs += __shfl_xor(rs, 16);                                                     \
    rs += __shfl_xor(rs, 32);                                                     \
    lrun = lrun * alpha + rs;                                                     \
    _Pragma("unroll")                                                             \
    for (int n = 0; n < 4; ++n)                                                   \
      _Pragma("unroll")                                                           \
      for (int r = 0; r < 4; ++r) accO[n][r] *= alpha;                            \
    const u32 w0 = pack2(S0[0], S0[1]);                                           \
    const u32 w1 = pack2(S0[2], S0[3]);                                           \
    const u32 w2 = pack2(S1[0], S1[1]);                                           \
    const u32 w3 = pack2(S1[2], S1[3]);                                           \
    const int s0 = ((g & 1) << 5) + l15;                                          \
    const int s1 = s0 + 16;                                                       \
    const u32 a0 = (u32)__shfl((int)w0, s0);                                      \
    const u32 a1 = (u32)__shfl((int)w2, s0);                                      \
    const u32 b0 = (u32)__shfl((int)w1, s0);                                      \
    const u32 b1 = (u32)__shfl((int)w3, s0);                                      \
    const u32 c0 = (u32)__shfl((int)w0, s1);                                      \
    const u32 c1 = (u32)__shfl((int)w2, s1);                                      \
    const u32 d0 = (u32)__shfl((int)w1, s1);                                      \
    const u32 d1 = (u32)__shfl((int)w3, s1);                                      \
    union { u32 u[4]; bf16x8 b; } pb;                                             \
    pb.u[0] = (g & 2) ? a1 : a0;                                                  \
    pb.u[1] = (g & 2) ? b1 : b0;                                                  \
    pb.u[2] = (g & 2) ? c1 : c0;                                                  \
    pb.u[3] = (g & 2) ? d1 : d0;                                                  \
    __builtin_amdgcn_s_setprio(1);                                                \
    _Pragma("unroll")                                                             \
    for (int n = 0; n < 4; ++n) accO[n] = MFMA16(av[n], pb.b, accO[n]);           \
    __builtin_amdgcn_s_setprio(0);                                                \
  }

  int jt = 0;
  for (;;) {
    ATTN_STEP(kA0, kA1, kB0, kB1);
    if (++jt > jt_max) break;
    ATTN_STEP(kB0, kB1, kA0, kA1);
    if (++jt > jt_max) break;
  }
#undef ATTN_STEP

  const float inv = 1.0f / lrun;
  u32* dst = (u32*)(AO + (size_t)q_glob * 1024 + h * 64 + g * 4);
#pragma unroll
  for (int n = 0; n < 4; ++n) {
    const u32 lo = pack2(accO[n][0] * inv, accO[n][1] * inv);
    const u32 hi = pack2(accO[n][2] * inv, accO[n][3] * inv);
    dst[n * 8 + 0] = lo;   // +n*16 u16 = +n*8 u32
    dst[n * 8 + 1] = hi;
  }
}

// ---------------- GEMM out: AO @ WoutT + bout  (M=2048, N=1024, K=1024) ----------------
__global__ __launch_bounds__(256) void k_gemm_out(const u16* __restrict__ AO, const u16* __restrict__ WoT,
                                                  const float* __restrict__ bout, float* __restrict__ out) {
  __shared__ __align__(16) u16 ldsA[128 * 64];
  __shared__ __align__(16) u16 ldsB[64 * 64];
  const int bid = blockIdx.x;                     // 256 blocks
  const int bn = bid & 15, bm = bid >> 4;
  f32x4 acc[4][2];
#pragma unroll
  for (int m = 0; m < 4; ++m)
#pragma unroll
    for (int n = 0; n < 2; ++n) acc[m][n] = (f32x4){0.f, 0.f, 0.f, 0.f};
  gemm_core_128x64(AO, WoT, bm * 128, bn * 64, 1024, ldsA, ldsB, acc);

  const int tid = threadIdx.x;
  const int wave = tid >> 6, lane = tid & 63;
  const int wr = wave >> 1, wc = wave & 1;
  const int g = lane >> 4, l15 = lane & 15;
  const int tbase = bm * 128 + wr * 64 + g * 4;
  const int cbase = bn * 64 + wc * 32 + l15;
#pragma unroll
  for (int m = 0; m < 4; ++m)
#pragma unroll
    for (int n = 0; n < 2; ++n) {
      const int c = cbase + n * 16;
      const float bb = bout[c];
#pragma unroll
      for (int r = 0; r < 4; ++r) {
        const int t = tbase + m * 16 + r;
        out[(size_t)t * 1024 + c] = acc[m][n][r] + bb;
      }
    }
}

// ---------------- launch ----------------
extern "C" void kernel_launch(void* const* d_in, const int* in_sizes, int n_in,
                              void* d_out, int out_size, void* d_ws, size_t ws_size,
                              hipStream_t stream) {
  const float* x      = (const float*)d_in[0];
  const float* Wqkv   = (const float*)d_in[1];
  const float* bqkv   = (const float*)d_in[2];
  const float* W1p    = (const float*)d_in[3];
  const float* W2p    = (const float*)d_in[4];
  const float* pscale = (const float*)d_in[5];
  const float* Wout   = (const float*)d_in[6];
  const float* bout   = (const float*)d_in[7];
  float* out = (float*)d_out;

  char* ws = (char*)d_ws;
  u16*   WB    = (u16*)(ws + 0);          // [3200][1024] bf16 (transposed weights)
  u16*   WoT   = (u16*)(ws + 6553600);    // [1024][1024] bf16
  u16*   xb    = (u16*)(ws + 8650752);    // [2048][1024] bf16
  u16*   Qext  = (u16*)(ws + 12845056);   // [16][2048][96] bf16 (q/8 | s*L | 0)
  u16*   Kext  = (u16*)(ws + 19136512);   // [16][2048][96] bf16 (k | J·L | 0)
  u16*   Vt    = (u16*)(ws + 25427968);   // [16][64][2048] bf16
  float* P12   = (float*)(ws + 29622272); // [2048][128] f32
  u16*   AO    = (u16*)(ws + 30670848);   // [2048][1024] bf16

  k_transpose_f32_bf16<<<dim3(96, 32), 256, 0, stream>>>(Wqkv, WB, 1024, 3072);
  k_pw<<<512, 256, 0, stream>>>(W1p, W2p, WB + (size_t)3072 * 1024);
  k_transpose_f32_bf16<<<dim3(32, 32), 256, 0, stream>>>(Wout, WoT, 1024, 1024);
  k_conv_x<<<2048, 256, 0, stream>>>(x, xb);
  k_gemm_qkvp<<<800, 256, 0, stream>>>(xb, WB, bqkv, Qext, Kext, Vt, P12);
  k_lines<<<128, 256, 0, stream>>>(P12, pscale, Qext, Kext);
  k_attn<<<512, 256, 0, stream>>>(Qext, Kext, Vt, AO);
  k_gemm_out<<<256, 256, 0, stream>>>(AO, WoT, bout, out);
}